// Round 7
// baseline (56.903 us; speedup 1.0000x reference)
//
#include <hip/hip_runtime.h>
#include <hip/hip_bf16.h>

// GQA paged-prefill attention, MI355X gfx950.
// Causal mask j<=i over concat(past,new) => only first Q_LEN (=1024) gathered
// past tokens are live. Flash-attention over tokens 0..1023 of paged cache.
//
// R7: (row x head) fattened blocks. Block = 64-row q-tile x 2 query heads
// (same kv head). 4 waves; wave owns 32 rows (2 row-tiles) of one head.
// Each K/V LDS fragment read feeds 2 MFMAs (reused across row-tiles) =>
// LDS read traffic per output row halves. Grid 256 = 1 block/CU.
// Staging via global_load_lds from prep'd swizzled bf16 KV (R6 prep).

#define NUM_HEADS 32
#define HEAD_DIM 128
#define Q_STRIDE 4096
#define SCALE 0.08838834764831845f
#define RESCALE_THR 8.0f
#define KSW_TILE 16384                 // bytes per (hkv, jb) tile
#define VSW_OFF (2 * 1024 * 1024)      // Vt tiles start 2MB into ws

typedef short short8 __attribute__((ext_vector_type(8)));
typedef float f32x4 __attribute__((ext_vector_type(4)));
typedef unsigned short ushort_t;
typedef unsigned int uint_t;

__device__ __forceinline__ ushort_t f2bf(float f) {
    return __builtin_bit_cast(ushort_t, __float2bfloat16(f));
}
__device__ __forceinline__ uint_t pk2(float a, float b) {
    return (uint_t)f2bf(a) | ((uint_t)f2bf(b) << 16);
}

// ---------------- prep: paged fp32 -> dense swizzled bf16 ----------------
__launch_bounds__(256)
__global__ void prep_kv(const float* __restrict__ kvc,
                        const int* __restrict__ bt,
                        char* __restrict__ wsb)
{
    __shared__ float sVt[64 * 128];
    const int blk = blockIdx.x;        // 128 blocks = hkv(8) x jb(16)
    const int hkv = blk >> 4;
    const int jb  = blk & 15;
    const int tid = threadIdx.x;
    char* kout = wsb + (size_t)(hkv * 16 + jb) * KSW_TILE;
    char* vout = wsb + VSW_OFF + (size_t)(hkv * 16 + jb) * KSW_TILE;

    // K: [t 64][d 128] bf16, 16B chunk c at byte t*256 + ((c*16)^((t&7)<<4))
#pragma unroll
    for (int i = 0; i < 4; ++i) {
        const int u = tid + i * 256;   // t(64) x c(16)
        const int t = u >> 4, c = u & 15;
        const int gtok = jb * 64 + t;
        const int page = bt[gtok >> 4];
        const float* src = kvc + (size_t)page * 32768 + (size_t)hkv * 2048
                         + (gtok & 15) * 128 + c * 8;
        float4 a = *(const float4*)src;
        float4 b = *(const float4*)(src + 4);
        uint4 p;
        p.x = pk2(a.x, a.y); p.y = pk2(a.z, a.w);
        p.z = pk2(b.x, b.y); p.w = pk2(b.z, b.w);
        *(uint4*)(kout + t * 256 + ((c * 16) ^ ((t & 7) << 4))) = p;
    }
    // V: coalesced fp32 read -> LDS
#pragma unroll
    for (int i = 0; i < 8; ++i) {
        const int u = tid + i * 256;   // t(64) x c4(32)
        const int t = u >> 5, c4 = u & 31;
        const int gtok = jb * 64 + t;
        const int page = bt[gtok >> 4];
        const float* src = kvc + (size_t)page * 32768 + 16384
                         + (size_t)hkv * 2048 + (gtok & 15) * 128 + c4 * 4;
        *(float4*)(sVt + t * 128 + c4 * 4) = *(const float4*)src;
    }
    __syncthreads();
    // Vt: [d 128][t 64] bf16, 16B chunk ch at byte (d*128+16*ch)^((d&7)<<4)
#pragma unroll
    for (int i = 0; i < 4; ++i) {
        const int u = tid + i * 256;   // d(128) x ch(8)
        const int d = u >> 3, ch = u & 7;
        float v[8];
#pragma unroll
        for (int k = 0; k < 8; ++k) v[k] = sVt[(8 * ch + k) * 128 + d];
        uint4 p;
        p.x = pk2(v[0], v[1]); p.y = pk2(v[2], v[3]);
        p.z = pk2(v[4], v[5]); p.w = pk2(v[6], v[7]);
        *(uint4*)(vout + ((d * 128 + 16 * ch) ^ ((d & 7) << 4))) = p;
    }
}

// ---------------- main attention ----------------
#define GLL16(G, L) __builtin_amdgcn_global_load_lds(                         \
    (const uint_t __attribute__((address_space(1)))*)(G),                     \
    (uint_t __attribute__((address_space(3)))*)(L), 16, 0, 0)

// Stage tile JB: linear DMA; swizzle baked into the global layout.
#define STAGE(JB, KB, VB) {                                                   \
    const char* ks = kvbf + (size_t)(hkv * 16 + (JB)) * KSW_TILE              \
                   + w * 4096 + lane * 16;                                    \
    const char* vs = ks + VSW_OFF;                                            \
    _Pragma("unroll")                                                         \
    for (int i = 0; i < 4; ++i) {                                             \
        GLL16(ks + i * 1024, (KB) + w * 4096 + i * 1024);                     \
        GLL16(vs + i * 1024, (VB) + w * 4096 + i * 1024);                     \
    }                                                                         \
}

__launch_bounds__(256)
__global__ void attn_main(const float* __restrict__ q,
                          const char* __restrict__ kvbf,
                          float* __restrict__ out)
{
    __shared__ __align__(16) char sK[2][16384];
    __shared__ __align__(16) char sV[2][16384];
    __shared__ __align__(16) char sP[4][2][2048];   // per wave, per row-tile

    const int bid = blockIdx.x;        // 256 blocks = qt(16) x head-pair(16)
    const int hp  = bid & 15;
    const int qt  = 15 - (bid >> 4);   // long blocks first
    const int hkv = hp >> 1;
    const int tid  = threadIdx.x;
    const int w    = tid >> 6;
    const int lane = tid & 63;
    const int l15  = lane & 15;
    const int lhi  = lane >> 4;
    const int h    = hp * 2 + (w >> 1);   // this wave's query head
    const int rh   = w & 1;               // row half: rows rh*32 .. rh*32+31

    // ---- Q fragments (SCALE folded): row-tile rt covers rows
    //      qt*64 + rh*32 + rt*16 + l15
    short8 qf[2][4];
#pragma unroll
    for (int rt = 0; rt < 2; ++rt) {
        const int qrow = qt * 64 + rh * 32 + rt * 16 + l15;
        const float* qp = q + (size_t)qrow * Q_STRIDE + h * HEAD_DIM;
#pragma unroll
        for (int s = 0; s < 4; ++s) {
            const int d0 = s * 32 + lhi * 8;
            float4 a = *(const float4*)(qp + d0);
            float4 b = *(const float4*)(qp + d0 + 4);
            short8 v;
            v[0] = (short)f2bf(a.x * SCALE); v[1] = (short)f2bf(a.y * SCALE);
            v[2] = (short)f2bf(a.z * SCALE); v[3] = (short)f2bf(a.w * SCALE);
            v[4] = (short)f2bf(b.x * SCALE); v[5] = (short)f2bf(b.y * SCALE);
            v[6] = (short)f2bf(b.z * SCALE); v[7] = (short)f2bf(b.w * SCALE);
            qf[rt][s] = v;
        }
    }

    f32x4 acc[2][8];
#pragma unroll
    for (int rt = 0; rt < 2; ++rt)
#pragma unroll
        for (int n2 = 0; n2 < 8; ++n2) acc[rt][n2] = (f32x4){0.f, 0.f, 0.f, 0.f};
    float m_run[2][4]  = {{-1e30f,-1e30f,-1e30f,-1e30f},{-1e30f,-1e30f,-1e30f,-1e30f}};
    float l_part[2][4] = {{0.f,0.f,0.f,0.f},{0.f,0.f,0.f,0.f}};

    // prologue: tile 0 -> buf 0 (syncthreads drains vmcnt incl. gll)
    STAGE(0, sK[0], sV[0])
    __syncthreads();

    for (int jb = 0; jb <= qt; ++jb) {
        const int cur = jb & 1;
        char* kbuf = sK[cur];
        char* vbuf = sV[cur];
        const bool pf = (jb < qt);
        if (pf) {           // DMA next tile into other buffer; flies under compute
            STAGE(jb + 1, sK[cur ^ 1], sV[cur ^ 1])
        }

        // ---- S = Q K^T : each K fragment read feeds BOTH row-tiles
        f32x4 sacc[2][4];
#pragma unroll
        for (int rt = 0; rt < 2; ++rt)
#pragma unroll
            for (int n = 0; n < 4; ++n) sacc[rt][n] = (f32x4){0.f, 0.f, 0.f, 0.f};
#pragma unroll
        for (int s = 0; s < 4; ++s) {
#pragma unroll
            for (int n = 0; n < 4; ++n) {
                const int tok = n * 16 + l15;
                const uint_t byte = (uint_t)(tok * 256)
                    + (((uint_t)((s * 32 + lhi * 8) * 2)) ^ ((uint_t)((tok & 7) << 4)));
                short8 kb = *(const short8*)(kbuf + byte);
                sacc[0][n] = __builtin_amdgcn_mfma_f32_16x16x32_bf16(qf[0][s], kb, sacc[0][n], 0, 0, 0);
                sacc[1][n] = __builtin_amdgcn_mfma_f32_16x16x32_bf16(qf[1][s], kb, sacc[1][n], 0, 0, 0);
            }
        }

        // ---- softmax with deferred max, in place on sacc
        const bool diag = (jb == qt);
#pragma unroll
        for (int rt = 0; rt < 2; ++rt) {
            if (diag) {
#pragma unroll
                for (int n = 0; n < 4; ++n)
#pragma unroll
                    for (int j = 0; j < 4; ++j) {
                        const int tok = jb * 64 + n * 16 + l15;
                        const int qg  = qt * 64 + rh * 32 + rt * 16 + lhi * 4 + j;
                        if (tok > qg) sacc[rt][n][j] = -1e30f;
                    }
            }
#pragma unroll
            for (int j = 0; j < 4; ++j) {
                float lmax = fmaxf(fmaxf(sacc[rt][0][j], sacc[rt][1][j]),
                                   fmaxf(sacc[rt][2][j], sacc[rt][3][j]));
                if (__any(lmax > m_run[rt][j] + RESCALE_THR)) {
                    float mt = lmax;
#pragma unroll
                    for (int off = 1; off < 16; off <<= 1)
                        mt = fmaxf(mt, __shfl_xor(mt, off));
                    const float mn = fmaxf(m_run[rt][j], mt);
                    const float alpha = __expf(m_run[rt][j] - mn);
                    m_run[rt][j] = mn;
                    l_part[rt][j] *= alpha;
#pragma unroll
                    for (int n2 = 0; n2 < 8; ++n2) acc[rt][n2][j] *= alpha;
                }
                float ls = 0.f;
#pragma unroll
                for (int n = 0; n < 4; ++n) {
                    float p = __expf(sacc[rt][n][j] - m_run[rt][j]);
                    sacc[rt][n][j] = p;
                    ls += p;
                }
                l_part[rt][j] += ls;
            }

            // ---- P -> per-wave per-row-tile LDS (A-fragment relayout)
            char* pb = sP[w][rt];
#pragma unroll
            for (int n = 0; n < 4; ++n)
#pragma unroll
                for (int j = 0; j < 4; ++j) {
                    const int r = lhi * 4 + j;
                    const uint_t byte = (uint_t)(r * 128)
                        + (((uint_t)((n * 16 + l15) * 2)) ^ ((uint_t)((r & 7) << 4)));
                    *(ushort_t*)(pb + byte) = f2bf(sacc[rt][n][j]);
                }
        }

        // ---- O += P V : each V fragment read feeds BOTH row-tiles
#pragma unroll
        for (int s2 = 0; s2 < 2; ++s2) {
            const uint_t pbyte = (uint_t)(l15 * 128)
                + (((uint_t)((s2 * 32 + lhi * 8) * 2)) ^ ((uint_t)((l15 & 7) << 4)));
            short8 pa0 = *(const short8*)(sP[w][0] + pbyte);
            short8 pa1 = *(const short8*)(sP[w][1] + pbyte);
#pragma unroll
            for (int n2 = 0; n2 < 8; ++n2) {
                const int dim = n2 * 16 + l15;
                const uint_t vbyte = (uint_t)(dim * 128)
                    + (((uint_t)((s2 * 32 + lhi * 8) * 2)) ^ ((uint_t)((dim & 7) << 4)));
                short8 vbf = *(const short8*)(vbuf + vbyte);
                acc[0][n2] = __builtin_amdgcn_mfma_f32_16x16x32_bf16(pa0, vbf, acc[0][n2], 0, 0, 0);
                acc[1][n2] = __builtin_amdgcn_mfma_f32_16x16x32_bf16(pa1, vbf, acc[1][n2], 0, 0, 0);
            }
        }

        if (pf) __syncthreads();   // drains gll (vmcnt) + publishes next tile
    }

    // ---- epilogue: reduce per-lane l across 16-lane row group, store
#pragma unroll
    for (int rt = 0; rt < 2; ++rt)
#pragma unroll
    for (int j = 0; j < 4; ++j) {
        float lsum = l_part[rt][j];
#pragma unroll
        for (int off = 1; off < 16; off <<= 1)
            lsum += __shfl_xor(lsum, off);
        const float inv = 1.0f / lsum;
        const int qg = qt * 64 + rh * 32 + rt * 16 + lhi * 4 + j;
        float* dst = out + (size_t)qg * Q_STRIDE + h * HEAD_DIM;
#pragma unroll
        for (int n2 = 0; n2 < 8; ++n2)
            dst[n2 * 16 + l15] = acc[rt][n2][j] * inv;
    }
}

extern "C" void kernel_launch(void* const* d_in, const int* in_sizes, int n_in,
                              void* d_out, int out_size, void* d_ws, size_t ws_size,
                              hipStream_t stream) {
    const float* q   = (const float*)d_in[0];
    // d_in[1] (k) and d_in[2] (v) are dead under the reference's causal mask.
    const float* kvc = (const float*)d_in[3];
    const int*   bt  = (const int*)d_in[4];
    float* out = (float*)d_out;
    char*  wsb = (char*)d_ws;
    prep_kv<<<dim3(128), dim3(256), 0, stream>>>(kvc, bt, wsb);
    attn_main<<<dim3(256), dim3(256), 0, stream>>>(q, wsb, out);
}

// Round 8
// 54.374 us; speedup vs baseline: 1.0465x; 1.0465x over previous
//
#include <hip/hip_runtime.h>
#include <hip/hip_bf16.h>

// GQA paged-prefill attention, MI355X gfx950.
// Causal mask j<=i over concat(past,new) => only first Q_LEN (=1024) gathered
// past tokens are live. Flash-attention over tokens 0..1023 of paged cache.
//
// R8: kv-split x head-pair x 8-wave blocks.
//  prep_kv: paged fp32 -> dense swizzled bf16 in ws (as R6).
//  attn_main: 512 blocks = 16 qt x 16 head-pairs x 2 kv-halves; 512 thr =
//    8 waves = 2 heads x 4 row-groups; LDS 80KB -> 2 blocks/CU -> 16 waves/CU
//    (4/SIMD, 2x R6 TLP). Half0 -> unnormalized acc in out + (m,l) in ws;
//    half1 -> bf16 acc + (m,l) in ws.
//  attn_combine: merges the two partials per row.

#define Q_STRIDE 4096
#define SCALE 0.08838834764831845f
#define RESCALE_THR 8.0f
#define KSW_TILE 16384                     // bytes per (hkv, jb) tile
#define VSW_OFF  (2 * 1024 * 1024)         // Vt tiles at +2MB
#define ACC1_OFF (4 * 1024 * 1024)         // half1 acc bf16: 32768 rows x 256B
#define ML0_OFF  (ACC1_OFF + 32768 * 256)  // half0 (m,l): 32768 x 8B
#define ML1_OFF  (ML0_OFF + 32768 * 8)     // half1 (m,l): 32768 x 8B

typedef short short8 __attribute__((ext_vector_type(8)));
typedef float f32x4 __attribute__((ext_vector_type(4)));
typedef unsigned short ushort_t;
typedef unsigned int uint_t;

__device__ __forceinline__ ushort_t f2bf(float f) {
    return __builtin_bit_cast(ushort_t, __float2bfloat16(f));
}
__device__ __forceinline__ uint_t pk2(float a, float b) {
    return (uint_t)f2bf(a) | ((uint_t)f2bf(b) << 16);
}
__device__ __forceinline__ float bf2f(ushort_t u) {
    uint_t x = ((uint_t)u) << 16;
    return __builtin_bit_cast(float, x);
}

// ---------------- prep: paged fp32 -> dense swizzled bf16 ----------------
__launch_bounds__(256)
__global__ void prep_kv(const float* __restrict__ kvc,
                        const int* __restrict__ bt,
                        char* __restrict__ wsb)
{
    __shared__ float sVt[64 * 128];
    const int blk = blockIdx.x;        // 128 blocks = hkv(8) x jb(16)
    const int hkv = blk >> 4;
    const int jb  = blk & 15;
    const int tid = threadIdx.x;
    char* kout = wsb + (size_t)(hkv * 16 + jb) * KSW_TILE;
    char* vout = wsb + VSW_OFF + (size_t)(hkv * 16 + jb) * KSW_TILE;

    // K: [t 64][d 128] bf16, 16B chunk c at byte t*256 + ((c*16)^((t&7)<<4))
#pragma unroll
    for (int i = 0; i < 4; ++i) {
        const int u = tid + i * 256;   // t(64) x c(16)
        const int t = u >> 4, c = u & 15;
        const int gtok = jb * 64 + t;
        const int page = bt[gtok >> 4];
        const float* src = kvc + (size_t)page * 32768 + (size_t)hkv * 2048
                         + (gtok & 15) * 128 + c * 8;
        float4 a = *(const float4*)src;
        float4 b = *(const float4*)(src + 4);
        uint4 p;
        p.x = pk2(a.x, a.y); p.y = pk2(a.z, a.w);
        p.z = pk2(b.x, b.y); p.w = pk2(b.z, b.w);
        *(uint4*)(kout + t * 256 + ((c * 16) ^ ((t & 7) << 4))) = p;
    }
    // V: coalesced fp32 read -> LDS
#pragma unroll
    for (int i = 0; i < 8; ++i) {
        const int u = tid + i * 256;   // t(64) x c4(32)
        const int t = u >> 5, c4 = u & 31;
        const int gtok = jb * 64 + t;
        const int page = bt[gtok >> 4];
        const float* src = kvc + (size_t)page * 32768 + 16384
                         + (size_t)hkv * 2048 + (gtok & 15) * 128 + c4 * 4;
        *(float4*)(sVt + t * 128 + c4 * 4) = *(const float4*)src;
    }
    __syncthreads();
    // Vt: [d 128][t 64] bf16, 16B chunk ch at byte (d*128+16*ch)^((d&7)<<4)
#pragma unroll
    for (int i = 0; i < 4; ++i) {
        const int u = tid + i * 256;   // d(128) x ch(8)
        const int d = u >> 3, ch = u & 7;
        float v[8];
#pragma unroll
        for (int k = 0; k < 8; ++k) v[k] = sVt[(8 * ch + k) * 128 + d];
        uint4 p;
        p.x = pk2(v[0], v[1]); p.y = pk2(v[2], v[3]);
        p.z = pk2(v[4], v[5]); p.w = pk2(v[6], v[7]);
        *(uint4*)(vout + ((d * 128 + 16 * ch) ^ ((d & 7) << 4))) = p;
    }
}

// ---------------- main attention ----------------
#define GLL16(G, L) __builtin_amdgcn_global_load_lds(                         \
    (const uint_t __attribute__((address_space(1)))*)(G),                     \
    (uint_t __attribute__((address_space(3)))*)(L), 16, 0, 0)

// Stage tile JB with 8 waves: wave w covers bytes [w*1024,+1K) and +8192 of
// both K (16KB) and V (16KB). LDS dest wave-uniform base + lane*16.
#define STAGE(JB, KB, VB) {                                                   \
    const char* b_ = kvbf + (size_t)(hkv * 16 + (JB)) * KSW_TILE              \
                   + w * 1024 + lane * 16;                                    \
    GLL16(b_,                  (KB) + w * 1024);                              \
    GLL16(b_ + 8192,           (KB) + w * 1024 + 8192);                       \
    GLL16(b_ + VSW_OFF,        (VB) + w * 1024);                              \
    GLL16(b_ + VSW_OFF + 8192, (VB) + w * 1024 + 8192);                       \
}

__launch_bounds__(512)
__global__ void attn_main(const float* __restrict__ q,
                          const char* __restrict__ kvbf,
                          float* __restrict__ out,
                          char* __restrict__ wsb)
{
    __shared__ __align__(16) char sK[2][16384];
    __shared__ __align__(16) char sV[2][16384];
    __shared__ __align__(16) char sP[8][2048];   // per wave

    const int bid  = blockIdx.x;       // 512 = half(2) x g(16) x hp(16)
    const int half = bid >> 8;
    const int rr   = bid & 255;
    const int g    = rr >> 4;
    const int hp   = rr & 15;
    // pairing: CU gets bid c (half0, qt=15-g, long) + bid c+256 (half1, qt=g)
    const int qt   = half ? g : (15 - g);
    const int nt   = qt + 1;
    const int nt0  = (nt + 1) >> 1;
    const int jb0  = half ? nt0 : 0;
    const int jb1  = half ? nt  : nt0;
    const int hkv  = hp >> 1;
    const int tid  = threadIdx.x;
    const int w    = tid >> 6;         // wave 0..7
    const int lane = tid & 63;
    const int l15  = lane & 15;
    const int lhi  = lane >> 4;
    const int h    = hp * 2 + (w >> 2);   // this wave's query head
    const int rg   = w & 3;               // row-group: rows rg*16..rg*16+15

    // ---- Q fragments (SCALE folded): wave rows qt*64 + rg*16 + l15
    short8 qf[4];
    {
        const int qrow = qt * 64 + rg * 16 + l15;
        const float* qp = q + (size_t)qrow * Q_STRIDE + h * 128;
#pragma unroll
        for (int s = 0; s < 4; ++s) {
            const int d0 = s * 32 + lhi * 8;
            float4 a = *(const float4*)(qp + d0);
            float4 b = *(const float4*)(qp + d0 + 4);
            short8 v;
            v[0] = (short)f2bf(a.x * SCALE); v[1] = (short)f2bf(a.y * SCALE);
            v[2] = (short)f2bf(a.z * SCALE); v[3] = (short)f2bf(a.w * SCALE);
            v[4] = (short)f2bf(b.x * SCALE); v[5] = (short)f2bf(b.y * SCALE);
            v[6] = (short)f2bf(b.z * SCALE); v[7] = (short)f2bf(b.w * SCALE);
            qf[s] = v;
        }
    }

    f32x4 acc[8];
#pragma unroll
    for (int n2 = 0; n2 < 8; ++n2) acc[n2] = (f32x4){0.f, 0.f, 0.f, 0.f};
    float m_run[4]  = {-1e30f, -1e30f, -1e30f, -1e30f};
    float l_part[4] = {0.f, 0.f, 0.f, 0.f};

    if (jb0 < jb1) {
        STAGE(jb0, sK[0], sV[0])
    }
    __syncthreads();

    for (int jb = jb0; jb < jb1; ++jb) {
        const int cur = (jb - jb0) & 1;
        char* kbuf = sK[cur];
        char* vbuf = sV[cur];
        const bool pf = (jb + 1 < jb1);
        if (pf) {           // DMA next tile into other buffer; flies under compute
            STAGE(jb + 1, sK[cur ^ 1], sV[cur ^ 1])
        }

        // ---- S = Q K^T
        f32x4 sacc[4];
#pragma unroll
        for (int n = 0; n < 4; ++n) sacc[n] = (f32x4){0.f, 0.f, 0.f, 0.f};
#pragma unroll
        for (int s = 0; s < 4; ++s) {
#pragma unroll
            for (int n = 0; n < 4; ++n) {
                const int tok = n * 16 + l15;
                const uint_t byte = (uint_t)(tok * 256)
                    + (((uint_t)((s * 32 + lhi * 8) * 2)) ^ ((uint_t)((tok & 7) << 4)));
                short8 kb = *(const short8*)(kbuf + byte);
                sacc[n] = __builtin_amdgcn_mfma_f32_16x16x32_bf16(qf[s], kb, sacc[n], 0, 0, 0);
            }
        }

        // ---- softmax with deferred max, in place
        const bool diag = (jb == qt);
        if (diag) {
#pragma unroll
            for (int n = 0; n < 4; ++n)
#pragma unroll
                for (int j = 0; j < 4; ++j) {
                    const int tok = jb * 64 + n * 16 + l15;
                    const int qg  = qt * 64 + rg * 16 + lhi * 4 + j;
                    if (tok > qg) sacc[n][j] = -1e30f;
                }
        }
#pragma unroll
        for (int j = 0; j < 4; ++j) {
            float lmax = fmaxf(fmaxf(sacc[0][j], sacc[1][j]),
                               fmaxf(sacc[2][j], sacc[3][j]));
            if (__any(lmax > m_run[j] + RESCALE_THR)) {
                float mt = lmax;
#pragma unroll
                for (int off = 1; off < 16; off <<= 1)
                    mt = fmaxf(mt, __shfl_xor(mt, off));
                const float mn = fmaxf(m_run[j], mt);
                const float alpha = __expf(m_run[j] - mn);
                m_run[j] = mn;
                l_part[j] *= alpha;
#pragma unroll
                for (int n2 = 0; n2 < 8; ++n2) acc[n2][j] *= alpha;
            }
            float ls = 0.f;
#pragma unroll
            for (int n = 0; n < 4; ++n) {
                float p = __expf(sacc[n][j] - m_run[j]);
                sacc[n][j] = p;
                ls += p;
            }
            l_part[j] += ls;
        }

        // ---- P -> per-wave LDS (A-fragment relayout)
        char* pb = sP[w];
#pragma unroll
        for (int n = 0; n < 4; ++n)
#pragma unroll
            for (int j = 0; j < 4; ++j) {
                const int r = lhi * 4 + j;
                const uint_t byte = (uint_t)(r * 128)
                    + (((uint_t)((n * 16 + l15) * 2)) ^ ((uint_t)((r & 7) << 4)));
                *(ushort_t*)(pb + byte) = f2bf(sacc[n][j]);
            }

        // ---- O += P V
#pragma unroll
        for (int s2 = 0; s2 < 2; ++s2) {
            const uint_t pbyte = (uint_t)(l15 * 128)
                + (((uint_t)((s2 * 32 + lhi * 8) * 2)) ^ ((uint_t)((l15 & 7) << 4)));
            short8 pa = *(const short8*)(pb + pbyte);
#pragma unroll
            for (int n2 = 0; n2 < 8; ++n2) {
                const int dim = n2 * 16 + l15;
                const uint_t vbyte = (uint_t)(dim * 128)
                    + (((uint_t)((s2 * 32 + lhi * 8) * 2)) ^ ((uint_t)((dim & 7) << 4)));
                short8 vbf = *(const short8*)(vbuf + vbyte);
                acc[n2] = __builtin_amdgcn_mfma_f32_16x16x32_bf16(pa, vbf, acc[n2], 0, 0, 0);
            }
        }

        if (pf) __syncthreads();   // drains gll (vmcnt) + publishes next tile
    }

    // ---- epilogue: reduce l over the 16-lane row group, emit partials
#pragma unroll
    for (int j = 0; j < 4; ++j) {
        float lsum = l_part[j];
#pragma unroll
        for (int off = 1; off < 16; off <<= 1)
            lsum += __shfl_xor(lsum, off);
        const int row64 = rg * 16 + lhi * 4 + j;     // row within 64-row tile
        const int qg    = qt * 64 + row64;
        const int idx   = (qt * 32 + h) * 64 + row64;
        if (half == 0) {
            float* dst = out + (size_t)qg * Q_STRIDE + h * 128;
#pragma unroll
            for (int n2 = 0; n2 < 8; ++n2)
                dst[n2 * 16 + l15] = acc[n2][j];     // unnormalized
            if (l15 == 0) {
                float* ml = (float*)(wsb + ML0_OFF) + (size_t)idx * 2;
                ml[0] = m_run[j]; ml[1] = lsum;
            }
        } else {
            ushort_t* dst = (ushort_t*)(wsb + ACC1_OFF) + (size_t)idx * 128;
#pragma unroll
            for (int n2 = 0; n2 < 8; ++n2)
                dst[n2 * 16 + l15] = f2bf(acc[n2][j]);
            if (l15 == 0) {
                float* ml = (float*)(wsb + ML1_OFF) + (size_t)idx * 2;
                ml[0] = m_run[j]; ml[1] = lsum;
            }
        }
    }
}

// ---------------- combine ----------------
__launch_bounds__(256)
__global__ void attn_combine(float* __restrict__ out, const char* __restrict__ wsb)
{
    const int pid = blockIdx.x;           // 512 = (qt*32 + h)
    const int qt = pid >> 5;
    const int h  = pid & 31;
    const int tid = threadIdx.x;
    const int d4  = (tid & 31) * 4;
    const float* ml0b = (const float*)(wsb + ML0_OFF);
    const float* ml1b = (const float*)(wsb + ML1_OFF);
    const ushort_t* a1b = (const ushort_t*)(wsb + ACC1_OFF);

#pragma unroll
    for (int p = 0; p < 8; ++p) {
        const int r = (tid >> 5) + p * 8;            // row 0..63
        const size_t idx = (size_t)pid * 64 + r;
        const float m1 = ml0b[idx * 2], l1 = ml0b[idx * 2 + 1];
        const float m2 = ml1b[idx * 2], l2 = ml1b[idx * 2 + 1];
        const float m  = fmaxf(m1, m2);
        const float a1 = __expf(m1 - m), a2 = __expf(m2 - m);
        const float inv = 1.0f / (l1 * a1 + l2 * a2);
        float* o = out + (size_t)(qt * 64 + r) * Q_STRIDE + h * 128 + d4;
        const ushort_t* y4 = a1b + idx * 128 + d4;
        float4 x = *(const float4*)o;
        x.x = (x.x * a1 + bf2f(y4[0]) * a2) * inv;
        x.y = (x.y * a1 + bf2f(y4[1]) * a2) * inv;
        x.z = (x.z * a1 + bf2f(y4[2]) * a2) * inv;
        x.w = (x.w * a1 + bf2f(y4[3]) * a2) * inv;
        *(float4*)o = x;
    }
}

extern "C" void kernel_launch(void* const* d_in, const int* in_sizes, int n_in,
                              void* d_out, int out_size, void* d_ws, size_t ws_size,
                              hipStream_t stream) {
    const float* q   = (const float*)d_in[0];
    // d_in[1] (k) and d_in[2] (v) are dead under the reference's causal mask.
    const float* kvc = (const float*)d_in[3];
    const int*   bt  = (const int*)d_in[4];
    float* out = (float*)d_out;
    char*  wsb = (char*)d_ws;
    prep_kv<<<dim3(128), dim3(256), 0, stream>>>(kvc, bt, wsb);
    attn_main<<<dim3(512), dim3(512), 0, stream>>>(q, wsb, out, wsb);
    attn_combine<<<dim3(512), dim3(256), 0, stream>>>(out, wsb);
}